// Round 20
// baseline (71.832 us; speedup 1.0000x reference)
//
#include <hip/hip_runtime.h>
#include <hip/hip_bf16.h>

// ---------------------------------------------------------------------------
// Binary CNN forward (eval):
//  conv3x3(sign(x), sign(W1)) + b1 -> maxpool2x2 -> BN -> hardtanh -> sign
//  -> (MX-fp4 MFMA GEMM vs sign(W2)) + b2 -> BN -> hardtanh
//  -> fused W3 projection (atomic partial sums) -> +b3, log_softmax
//
// Signs are packed as fp4 e2m1 nibbles (+1 = 0x2, -1 = 0xA, pad = 0x0).
// mfma_scale_f32_32x32x64_f8f6f4 (fmt 4 = fp4, scale 127 = x1.0) gives the
// exact +-1 dot in f32 (integer partials <= 6272 < 2^24). Rows are padded
// 6272 -> 6400 nibbles (3200 B); pad nibbles are +0.0 and contribute 0.
//
// R20: stage1 amortization -- 512-thread blocks, 2 images per conv block
// (one weight-prep + one barrier pair + one LDS zero serve two images;
// 448/512 threads active in conv vs 224/256) and 2 W2-rows per pack block.
// Inner code verbatim from R19; explicit launch_bounds(512,2) guards the
// R13 VGPR-squeeze (scalar window needs ~48 VGPRs). mm_fp4 = proven R16
// kernel (39.8 us): BKB=128, XOR swizzle, drain barrier, w3s LDS staging
// (R18 lesson: scatter reads need LDS staging even when L2-resident).
// ---------------------------------------------------------------------------

#define EPS 1e-5f

typedef int i32x4 __attribute__((ext_vector_type(4)));
typedef int i32x8 __attribute__((ext_vector_type(8)));
typedef float f32x16 __attribute__((ext_vector_type(16)));

#define GLD_LDS(gsrc, ldst)                                                   \
  __builtin_amdgcn_global_load_lds(                                           \
      (const __attribute__((address_space(1))) void*)(gsrc),                  \
      (__attribute__((address_space(3))) void*)(ldst), 16, 0, 0)

// v_dot4_i32_i8: 4-way i8 dot + i32 acc in one instruction
#if defined(__has_builtin)
#if __has_builtin(__builtin_amdgcn_sdot4)
#define SDOT4(a, b, c) __builtin_amdgcn_sdot4((int)(a), (int)(b), (c), false)
#endif
#endif
#ifndef SDOT4
static __device__ __forceinline__ int sdot4_fb(int a, int b, int c) {
#pragma unroll
  for (int k = 0; k < 4; k++)
    c += ((int)(signed char)(a >> (8 * k))) * ((int)(signed char)(b >> (8 * k)));
  return c;
}
#define SDOT4(a, b, c) sdot4_fb((int)(a), (int)(b), (c))
#endif

#define RSTRIDE 3200  // bytes per row: 6272 nibbles + 64 B zero pad

// fp4 e2m1 encode of sign: >=0 -> +1.0 (0x2), else -1.0 (0xA)
__device__ __forceinline__ unsigned fp4s(float v) {
  return (v >= 0.f) ? 0x2u : 0xAu;
}

// ---------- Stage 1: 3072 blocks x 512 thr; 2 conv (2 images ea) : 1 pack ---
__global__ __launch_bounds__(512, 2) void stage1(
    const float* __restrict__ x, const float* __restrict__ W1,
    const float* __restrict__ b1, const float* __restrict__ g1,
    const float* __restrict__ be1, const float* __restrict__ m1,
    const float* __restrict__ v1, const float* __restrict__ W2,
    unsigned char* __restrict__ A4, unsigned char* __restrict__ B4,
    float* __restrict__ logits) {
  const int t = threadIdx.x;
  const int bid = blockIdx.x;
  const int trio = bid / 3, mod = bid - trio * 3;

  if (mod == 2) {
    // ---- pack 2 sign(W2) rows as fp4 nibbles: 256 threads per row ----
    const int row = trio * 2 + (t >> 8);   // trio in [0,1024) -> rows 0..2047
    const int t2 = t & 255;
    const float4* wr4 = (const float4*)(W2 + (long)row * 6272);
    unsigned char* br = B4 + (long)row * RSTRIDE;
#pragma unroll
    for (int i = 0; i < 4; i++) {
      int u = t2 + 256 * i;            // u-th group of 8 k-values
      if (u < 784) {
        float4 a = wr4[2 * u], b = wr4[2 * u + 1];
        unsigned w = (fp4s(a.x)) | (fp4s(a.y) << 4) | (fp4s(a.z) << 8) |
                     (fp4s(a.w) << 12) | (fp4s(b.x) << 16) | (fp4s(b.y) << 20) |
                     (fp4s(b.z) << 24) | (fp4s(b.w) << 28);
        *(unsigned*)(br + 4 * u) = w;
      }
    }
    if (t2 < 16) *(unsigned*)(br + 3136 + 4 * t2) = 0u;  // zero pad tail
    if (trio < 80) logits[trio * 512 + t] = 0.f;         // replaces memset
    return;
  }

  // ---- conv path: image pair p -> images 2p, 2p+1 ----
  const int p = trio * 2 + mod;          // pair index 0..2047
  __shared__ signed char sxb[2][30 * 36];  // padded binarized images
  __shared__ int wdw[32][3][2];            // weight dwords: [c][kh][dj]
  __shared__ float cAB[32][2];             // {cA, cB} per channel

  for (int i = t; i < 540; i += 512) ((int*)sxb)[i] = 0;  // zero incl. border
  __syncthreads();

  const float* xb = x + (long)(2 * p) * 784;
  for (int q = t; q < 1568; q += 512) {
    int img = q >> 9, pp = q - img * 784;   // q/784 via: img = (q >= 784)
    img = (q >= 784) ? 1 : 0;
    pp = q - img * 784;
    float v = xb[q];
    sxb[img][(pp / 28 + 1) * 36 + (pp % 28) + 1] =
        (v >= 0.f) ? (signed char)1 : (signed char)-1;
  }
  if (t < 96) {
    int c = t / 3, kh = t - c * 3;
    const float* wp = W1 + c * 9 + kh * 3;
    unsigned u0 = (wp[0] >= 0.f) ? 0x01u : 0xFFu;
    unsigned u1 = (wp[1] >= 0.f) ? 0x01u : 0xFFu;
    unsigned u2 = (wp[2] >= 0.f) ? 0x01u : 0xFFu;
    wdw[c][kh][0] = (int)((u2 << 16) | (u1 << 8) | u0);   // (w0,w1,w2,0)
    wdw[c][kh][1] = (int)((u2 << 24) | (u1 << 16) | (u0 << 8));  // (0,w0,w1,w2)
  }
  if (t < 32) {
    float sc = g1[t] * rsqrtf(v1[t] + EPS);
    cAB[t][0] = sc;
    cAB[t][1] = sc * (b1[t] - m1[t]) + be1[t];  // pred = cA*maxconv + cB >= 0
  }
  // zero the 64-byte pad tails of both images' A4 rows
  if (t < 32) {
    int img = t >> 4, w4 = t & 15;
    *(unsigned*)(A4 + (long)(2 * p + img) * RSTRIDE + 3136 + 4 * w4) = 0u;
  }
  __syncthreads();

  // one thread per (image, channel, pooled-row-pair): 448 active.
  if (t < 448) {
    const int img = t / 224, tt = t - img * 224;
    const int c = tt / 7, h2 = tt - c * 7;
    const signed char* sx = sxb[img];
    const unsigned* r0 = (const unsigned*)&sx[(4 * h2 + 0) * 36];
    const unsigned* r1 = (const unsigned*)&sx[(4 * h2 + 1) * 36];
    const unsigned* r2 = (const unsigned*)&sx[(4 * h2 + 2) * 36];
    const unsigned* r3 = (const unsigned*)&sx[(4 * h2 + 3) * 36];
    const unsigned* r4 = (const unsigned*)&sx[(4 * h2 + 4) * 36];
    const unsigned* r5 = (const unsigned*)&sx[(4 * h2 + 5) * 36];

    const int w00 = wdw[c][0][0], w01 = wdw[c][0][1];
    const int w10 = wdw[c][1][0], w11 = wdw[c][1][1];
    const int w20 = wdw[c][2][0], w21 = wdw[c][2][1];
    const float scA = cAB[c][0], scB = cAB[c][1];

    auto cmax = [&](unsigned p0, unsigned p1, unsigned p2, unsigned p3) {
      int c00 = SDOT4(p0, w00, SDOT4(p1, w10, SDOT4(p2, w20, 0)));
      int c01 = SDOT4(p0, w01, SDOT4(p1, w11, SDOT4(p2, w21, 0)));
      int c10 = SDOT4(p1, w00, SDOT4(p2, w10, SDOT4(p3, w20, 0)));
      int c11 = SDOT4(p1, w01, SDOT4(p2, w11, SDOT4(p3, w21, 0)));
      return max(max(c00, c01), max(c10, c11));
    };
    auto mid = [](unsigned lo, unsigned hi) {  // bytes 2..5 of (hi:lo)
      return (unsigned)((((unsigned long long)hi << 32) | lo) >> 16);
    };
    auto nib = [&](int mx) {
      return (scA * (float)mx + scB >= 0.f) ? 0x2u : 0xAu;
    };

    unsigned c0 = r0[0], c1 = r1[0], c2 = r2[0];
    unsigned c3 = r3[0], c4 = r4[0], c5 = r5[0];
    unsigned long long b0 = 0ull, b1acc = 0ull;
#pragma unroll
    for (int j = 0; j < 7; j++) {      // dword j -> positions w = 2j, 2j+1
      unsigned n0 = r0[j + 1], n1 = r1[j + 1], n2 = r2[j + 1];
      unsigned n3 = r3[j + 1], n4 = r4[j + 1], n5 = r5[j + 1];
      unsigned q0 = mid(c0, n0), q1 = mid(c1, n1), q2 = mid(c2, n2);
      unsigned q3 = mid(c3, n3), q4 = mid(c4, n4), q5 = mid(c5, n5);
      unsigned by0 = nib(cmax(c0, c1, c2, c3)) |        // h=2h2,   w=2j
                     (nib(cmax(q0, q1, q2, q3)) << 4);  // h=2h2,   w=2j+1
      unsigned by1 = nib(cmax(c2, c3, c4, c5)) |        // h=2h2+1, w=2j
                     (nib(cmax(q2, q3, q4, q5)) << 4);  // h=2h2+1, w=2j+1
      b0 |= (unsigned long long)by0 << (8 * j);
      b1acc |= (unsigned long long)by1 << (8 * j);
      c0 = n0; c1 = n1; c2 = n2; c3 = n3; c4 = n4; c5 = n5;
    }
    // bytes: row 2h2 at base..+6, row 2h2+1 at +7..+13 (2-aligned base)
    unsigned char* pw = A4 + (long)(2 * p + img) * RSTRIDE + c * 98 + h2 * 14;
    *(unsigned short*)(pw + 0)  = (unsigned short)b0;
    *(unsigned short*)(pw + 2)  = (unsigned short)(b0 >> 16);
    *(unsigned short*)(pw + 4)  = (unsigned short)(b0 >> 32);
    *(unsigned short*)(pw + 6)  =
        (unsigned short)(((b0 >> 48) & 0xFFull) | ((b1acc & 0xFFull) << 8));
    *(unsigned short*)(pw + 8)  = (unsigned short)(b1acc >> 8);
    *(unsigned short*)(pw + 10) = (unsigned short)(b1acc >> 24);
    *(unsigned short*)(pw + 12) = (unsigned short)(b1acc >> 40);
  }
}

// ---------- MX-fp4 MFMA GEMM 4096x2048 (K=6400 nib) + BN2 + clip + W3 -------
#define TM 128
#define TN 128
#define BKB 128   // bytes per chunk per row = K 256 nibbles
#define NKC 25    // 3200 / 128

// LDS map:
//  [0,32768)     : buffer 0 (sA 16K | sB 16K)   (tiles: 128 rows x 128 B)
//  [32768,65536) : buffer 1
//  [0,34816)     : epilogue overlay zb[128][136] bf16 (after main loop)
//  [65536,70816) : w3s[10][132] f32
__global__ __launch_bounds__(256, 2) void mm_fp4(
    const unsigned char* __restrict__ A4, const unsigned char* __restrict__ B4,
    const float* __restrict__ b2, const float* __restrict__ g2,
    const float* __restrict__ be2, const float* __restrict__ m2,
    const float* __restrict__ v2, const float* __restrict__ W3,
    float* __restrict__ logits) {
  __shared__ __align__(16) char smem[70816];
  float* w3s = (float*)(smem + 65536);

  const int t = threadIdx.x;
  const int lane = t & 63, wv = t >> 6;
  const int l31 = lane & 31, lh = lane >> 5;
  const int wr = wv >> 1, wc = wv & 1;   // 2x2 wave grid, 64x64 wave tile

  // XCD-aware block swizzle: 512 blocks, 8 XCDs -> each XCD gets 64
  // consecutive swz = 4 M-panels x 16 N-panels.
  const int bid = blockIdx.x;
  const int swz = (bid & 7) * 64 + (bid >> 3);
  const long tileM = (long)(swz >> 4) * TM;
  const long tileN = (long)(swz & 15) * TN;

  // w3s staging: one coalesced 5 KB load per block. The epilogue's read
  // pattern (cls varies per lane -> 8 KB lane stride in W3) would be 64
  // L2 transactions per instruction if read from global (R18: +25 us).
  for (int i = t; i < 1320; i += 256) {
    int cls = i / 132, c = i - cls * 132;
    w3s[i] = (c < 128) ? W3[cls * 2048 + tileN + c] : 0.f;
  }

  // Stage chunk kc into buffer buf: 8 gld_lds per wave (4 A + 4 B).
  // LDS linear (r, sl): off = r*128 + sl*16, holding global slot sl^(r&7)
  // (inverse-swizzled source; frag read applies the same XOR). Proven R6 path.
  auto stage = [&](int buf, int kc) {
    const int kb = kc * BKB;
    char* base = smem + buf * 32768;
#pragma unroll
    for (int i = 0; i < 4; i++) {
      int seg = wv * 4 + i;            // 16 segments x 1 KB = 16 KB
      int o = seg * 1024 + lane * 16;
      int r = o >> 7, sl = (o >> 4) & 7;
      int goff = kb + ((sl ^ (r & 7)) << 4);
      GLD_LDS(A4 + (tileM + r) * RSTRIDE + goff, base + seg * 1024);
      GLD_LDS(B4 + (tileN + r) * RSTRIDE + goff, base + 16384 + seg * 1024);
    }
  };

  f32x16 acc[2][2];
#pragma unroll
  for (int a = 0; a < 2; a++)
#pragma unroll
    for (int q = 0; q < 2; q++) acc[a][q] = (f32x16)0.f;

  stage(0, 0);
  __syncthreads();   // compiler drains vmcnt before s_barrier

  int cur = 0;
  for (int kc = 0; kc < NKC; kc++) {
    if (kc + 1 < NKC) stage(cur ^ 1, kc + 1);  // prefetch overlaps compute
    const char* sAb = smem + cur * 32768;
    const char* sBb = sAb + 16384;
#pragma unroll
    for (int ks = 0; ks < 4; ks++) {   // 4 K-steps of 64 nibbles
      int slot = ks * 2 + lh;          // lane-half lh takes nibbles 0-31/32-63
      i32x8 af[2], bf[2];
#pragma unroll
      for (int mt = 0; mt < 2; mt++) {
        int r = wr * 64 + mt * 32 + l31;
        i32x4 v = *(const i32x4*)(sAb + r * 128 + ((slot ^ (r & 7)) << 4));
        af[mt] = (i32x8){v[0], v[1], v[2], v[3], 0, 0, 0, 0};
      }
#pragma unroll
      for (int nt = 0; nt < 2; nt++) {
        int r = wc * 64 + nt * 32 + l31;
        i32x4 v = *(const i32x4*)(sBb + r * 128 + ((slot ^ (r & 7)) << 4));
        bf[nt] = (i32x8){v[0], v[1], v[2], v[3], 0, 0, 0, 0};
      }
      __builtin_amdgcn_s_setprio(1);
#pragma unroll
      for (int mt = 0; mt < 2; mt++)
#pragma unroll
        for (int nt = 0; nt < 2; nt++)
          acc[mt][nt] = __builtin_amdgcn_mfma_scale_f32_32x32x64_f8f6f4(
              af[mt], bf[nt], acc[mt][nt],
              4, 4,            // cbsz / blgp: fmt 4 = fp4 (e2m1)
              0, 127,          // opsel_a, scale_a = E8M0 127 -> x1.0
              0, 127);         // opsel_b, scale_b
      __builtin_amdgcn_s_setprio(0);
    }
    __syncthreads();   // drains this wave's DMA (vmcnt) + guards buffer swap
    cur ^= 1;
  }

  // ---- epilogue: z = clip(BN2(dot)) as bf16 into LDS, then W3 partials -----
  unsigned short* zb = (unsigned short*)smem;  // [128][136] bf16 = 34816 B
#pragma unroll
  for (int mt = 0; mt < 2; mt++)
#pragma unroll
    for (int nt = 0; nt < 2; nt++) {
      int cl = wc * 64 + nt * 32 + l31;
      int col = (int)tileN + cl;
      float sc = g2[col] * rsqrtf(v2[col] + EPS);
      float off = sc * (b2[col] - m2[col]) + be2[col];
      int rbase = wr * 64 + mt * 32 + 4 * lh;
#pragma unroll
      for (int q = 0; q < 16; q++) {
        int rl = rbase + (q & 3) + 8 * (q >> 2);
        float zz = sc * acc[mt][nt][q] + off;
        zz = fminf(1.f, fmaxf(-1.f, zz));
        __hip_bfloat16 hb = __float2bfloat16(zz);
        zb[rl * 136 + cl] = *(unsigned short*)&hb;
      }
    }
  __syncthreads();

#pragma unroll
  for (int i = 0; i < 5; i++) {
    int task = t + i * 256;           // 1280 tasks = 128 rows x 10 classes
    int row = task / 10, cls = task - row * 10;
    float s = 0.f;
#pragma unroll
    for (int c8 = 0; c8 < 16; c8++) {
      uint4 zB = *(const uint4*)(zb + row * 136 + c8 * 8);  // 8 bf16
      const float* wp = w3s + cls * 132 + c8 * 8;
      float4 w0 = *(const float4*)wp;
      float4 w1 = *(const float4*)(wp + 4);
      s += __uint_as_float(zB.x << 16) * w0.x +
           __uint_as_float(zB.x & 0xffff0000u) * w0.y +
           __uint_as_float(zB.y << 16) * w0.z +
           __uint_as_float(zB.y & 0xffff0000u) * w0.w;
      s += __uint_as_float(zB.z << 16) * w1.x +
           __uint_as_float(zB.z & 0xffff0000u) * w1.y +
           __uint_as_float(zB.w << 16) * w1.z +
           __uint_as_float(zB.w & 0xffff0000u) * w1.w;
    }
    atomicAdd(&logits[(tileM + row) * 10 + cls], s);
  }
}

// ---------- +b3, log_softmax over logits[4096][10] -------------------------
__global__ __launch_bounds__(256) void lsm2(const float* __restrict__ logits,
                                            const float* __restrict__ b3,
                                            float* __restrict__ out) {
  int r = blockIdx.x * 256 + threadIdx.x;
  const float* lr = logits + r * 10;
  float v[10];
#pragma unroll
  for (int j = 0; j < 10; j++) v[j] = lr[j] + b3[j];
  float m = v[0];
#pragma unroll
  for (int j = 1; j < 10; j++) m = fmaxf(m, v[j]);
  float s = 0.f;
#pragma unroll
  for (int j = 0; j < 10; j++) s += expf(v[j] - m);
  float ls = logf(s);
#pragma unroll
  for (int j = 0; j < 10; j++) out[r * 10 + j] = v[j] - m - ls;
}

// ---------------------------------------------------------------------------
extern "C" void kernel_launch(void* const* d_in, const int* in_sizes, int n_in,
                              void* d_out, int out_size, void* d_ws, size_t ws_size,
                              hipStream_t stream) {
  const float* x   = (const float*)d_in[0];
  const float* W1  = (const float*)d_in[1];
  const float* b1  = (const float*)d_in[2];
  const float* g1  = (const float*)d_in[3];
  const float* be1 = (const float*)d_in[4];
  const float* m1  = (const float*)d_in[5];
  const float* v1  = (const float*)d_in[6];
  const float* W2  = (const float*)d_in[7];
  const float* b2  = (const float*)d_in[8];
  const float* g2  = (const float*)d_in[9];
  const float* be2 = (const float*)d_in[10];
  const float* m2  = (const float*)d_in[11];
  const float* v2  = (const float*)d_in[12];
  const float* W3  = (const float*)d_in[13];
  const float* b3  = (const float*)d_in[14];

  char* ws = (char*)d_ws;
  unsigned char* A4 = (unsigned char*)ws;               // 4096*3200 = 13,107,200 B
  unsigned char* B4 = (unsigned char*)(ws + 13107200);  // 2048*3200 = 6,553,600 B
  float* logits = (float*)(ws + 19660800);              // 4096*10*4 = 163,840 B

  stage1<<<3072, 512, 0, stream>>>(x, W1, b1, g1, be1, m1, v1, W2, A4, B4, logits);
  mm_fp4<<<512, 256, 0, stream>>>(A4, B4, b2, g2, be2, m2, v2, W3, logits);
  lsm2<<<16, 256, 0, stream>>>(logits, b3, (float*)d_out);
}

// Round 21
// 68.687 us; speedup vs baseline: 1.0458x; 1.0458x over previous
//
#include <hip/hip_runtime.h>
#include <hip/hip_bf16.h>

// ---------------------------------------------------------------------------
// Binary CNN forward (eval):
//  conv3x3(sign(x), sign(W1)) + b1 -> maxpool2x2 -> BN -> hardtanh -> sign
//  -> (MX-fp4 MFMA GEMM vs sign(W2)) + b2 -> BN -> hardtanh
//  -> fused W3 projection (atomic partial sums) -> +b3, log_softmax
//
// Signs are packed as fp4 e2m1 nibbles (+1 = 0x2, -1 = 0xA, pad = 0x0).
// mfma_scale_f32_32x32x64_f8f6f4 (fmt 4 = fp4, scale 127 = x1.0) gives the
// exact +-1 dot in f32 (integer partials <= 6272 < 2^24). Rows are padded
// 6272 -> 6400 nibbles (3200 B); pad nibbles are +0.0 and contribute 0.
//
// R21 = R19 verbatim (measured best: 68.7 us). Ledger: stage1 26.4 us
// (restructures R13-R15/R20 all regressed or matched), mm_fp4 39.8 us
// (schedule x3, operand-path x3, LDS-shape x2 attempts all regressed;
// w3s LDS staging essential -- R18's direct-W3 epilogue cost +25 us),
// lsm2 2.5 us. logits zeroing folded into stage1 (no memset dispatch).
// ---------------------------------------------------------------------------

#define EPS 1e-5f

typedef int i32x4 __attribute__((ext_vector_type(4)));
typedef int i32x8 __attribute__((ext_vector_type(8)));
typedef float f32x16 __attribute__((ext_vector_type(16)));

#define GLD_LDS(gsrc, ldst)                                                   \
  __builtin_amdgcn_global_load_lds(                                           \
      (const __attribute__((address_space(1))) void*)(gsrc),                  \
      (__attribute__((address_space(3))) void*)(ldst), 16, 0, 0)

// v_dot4_i32_i8: 4-way i8 dot + i32 acc in one instruction
#if defined(__has_builtin)
#if __has_builtin(__builtin_amdgcn_sdot4)
#define SDOT4(a, b, c) __builtin_amdgcn_sdot4((int)(a), (int)(b), (c), false)
#endif
#endif
#ifndef SDOT4
static __device__ __forceinline__ int sdot4_fb(int a, int b, int c) {
#pragma unroll
  for (int k = 0; k < 4; k++)
    c += ((int)(signed char)(a >> (8 * k))) * ((int)(signed char)(b >> (8 * k)));
  return c;
}
#define SDOT4(a, b, c) sdot4_fb((int)(a), (int)(b), (c))
#endif

#define RSTRIDE 3200  // bytes per row: 6272 nibbles + 64 B zero pad

// fp4 e2m1 encode of sign: >=0 -> +1.0 (0x2), else -1.0 (0xA)
__device__ __forceinline__ unsigned fp4s(float v) {
  return (v >= 0.f) ? 0x2u : 0xAu;
}

// ---------- Stage 1 (merged, interleaved 2 conv : 1 W2-pack per trio) -------
__global__ __launch_bounds__(256) void stage1(
    const float* __restrict__ x, const float* __restrict__ W1,
    const float* __restrict__ b1, const float* __restrict__ g1,
    const float* __restrict__ be1, const float* __restrict__ m1,
    const float* __restrict__ v1, const float* __restrict__ W2,
    unsigned char* __restrict__ A4, unsigned char* __restrict__ B4,
    float* __restrict__ logits) {
  const int t = threadIdx.x;
  const int bid = blockIdx.x;
  const int trio = bid / 3, mod = bid - trio * 3;

  if (mod == 2) {
    // ---- pack sign(W2) row as fp4 nibbles: 8 floats -> 4 bytes ----
    const int row = trio;
    const float4* wr4 = (const float4*)(W2 + (long)row * 6272);
    unsigned char* br = B4 + (long)row * RSTRIDE;
#pragma unroll
    for (int i = 0; i < 4; i++) {
      int u = t + 256 * i;             // u-th group of 8 k-values
      if (u < 784) {
        float4 a = wr4[2 * u], b = wr4[2 * u + 1];
        unsigned w = (fp4s(a.x)) | (fp4s(a.y) << 4) | (fp4s(a.z) << 8) |
                     (fp4s(a.w) << 12) | (fp4s(b.x) << 16) | (fp4s(b.y) << 20) |
                     (fp4s(b.z) << 24) | (fp4s(b.w) << 28);
        *(unsigned*)(br + 4 * u) = w;
      }
    }
    if (t < 16) *(unsigned*)(br + 3136 + 4 * t) = 0u;  // zero pad tail
    if (trio < 160) logits[trio * 256 + t] = 0.f;      // replaces memset
    return;
  }

  // ---- conv path: image b ----
  const int b = trio * 2 + mod;
  __shared__ signed char sxb[30 * 36];  // padded binarized image (36 B stride)
  __shared__ int wdw[32][3][2];         // weight dwords: [c][kh][dj]
  __shared__ float cAB[32][2];          // {cA, cB} per channel

  for (int i = t; i < 270; i += 256) ((int*)sxb)[i] = 0;  // zero incl. border
  __syncthreads();

  const float* xb = x + b * 784;
  for (int p = t; p < 784; p += 256) {
    float v = xb[p];
    sxb[(p / 28 + 1) * 36 + (p % 28) + 1] = (v >= 0.f) ? (signed char)1
                                                       : (signed char)-1;
  }
  if (t < 96) {
    int c = t / 3, kh = t - c * 3;
    const float* wp = W1 + c * 9 + kh * 3;
    unsigned u0 = (wp[0] >= 0.f) ? 0x01u : 0xFFu;
    unsigned u1 = (wp[1] >= 0.f) ? 0x01u : 0xFFu;
    unsigned u2 = (wp[2] >= 0.f) ? 0x01u : 0xFFu;
    wdw[c][kh][0] = (int)((u2 << 16) | (u1 << 8) | u0);   // (w0,w1,w2,0)
    wdw[c][kh][1] = (int)((u2 << 24) | (u1 << 16) | (u0 << 8));  // (0,w0,w1,w2)
  }
  if (t < 32) {
    float sc = g1[t] * rsqrtf(v1[t] + EPS);
    cAB[t][0] = sc;
    cAB[t][1] = sc * (b1[t] - m1[t]) + be1[t];  // pred = cA*maxconv + cB >= 0
  }
  // zero the 64-byte pad tail of this image's A4 row (disjoint from conv
  // writes below -> no sync needed)
  if (t < 16) *(unsigned*)(A4 + (long)b * RSTRIDE + 3136 + 4 * t) = 0u;
  __syncthreads();

  // one thread per (channel, pooled-row-pair): c = t/7, h2 = t%7 -> pooled
  // rows 2*h2, 2*h2+1 needing input rows 4*h2 .. 4*h2+5. Row window kept in
  // NAMED SCALARS (no arrays -> no scratch). Output nibbles accumulate in
  // two u64s and store directly to A4 (14 contiguous bytes, 7 u16 stores).
  if (t < 224) {
    const int c = t / 7, h2 = t - c * 7;
    const unsigned* r0 = (const unsigned*)&sxb[(4 * h2 + 0) * 36];
    const unsigned* r1 = (const unsigned*)&sxb[(4 * h2 + 1) * 36];
    const unsigned* r2 = (const unsigned*)&sxb[(4 * h2 + 2) * 36];
    const unsigned* r3 = (const unsigned*)&sxb[(4 * h2 + 3) * 36];
    const unsigned* r4 = (const unsigned*)&sxb[(4 * h2 + 4) * 36];
    const unsigned* r5 = (const unsigned*)&sxb[(4 * h2 + 5) * 36];

    const int w00 = wdw[c][0][0], w01 = wdw[c][0][1];
    const int w10 = wdw[c][1][0], w11 = wdw[c][1][1];
    const int w20 = wdw[c][2][0], w21 = wdw[c][2][1];
    const float scA = cAB[c][0], scB = cAB[c][1];

    auto cmax = [&](unsigned p0, unsigned p1, unsigned p2, unsigned p3) {
      int c00 = SDOT4(p0, w00, SDOT4(p1, w10, SDOT4(p2, w20, 0)));
      int c01 = SDOT4(p0, w01, SDOT4(p1, w11, SDOT4(p2, w21, 0)));
      int c10 = SDOT4(p1, w00, SDOT4(p2, w10, SDOT4(p3, w20, 0)));
      int c11 = SDOT4(p1, w01, SDOT4(p2, w11, SDOT4(p3, w21, 0)));
      return max(max(c00, c01), max(c10, c11));
    };
    auto mid = [](unsigned lo, unsigned hi) {  // bytes 2..5 of (hi:lo)
      return (unsigned)((((unsigned long long)hi << 32) | lo) >> 16);
    };
    auto nib = [&](int mx) {
      return (scA * (float)mx + scB >= 0.f) ? 0x2u : 0xAu;
    };

    unsigned c0 = r0[0], c1 = r1[0], c2 = r2[0];
    unsigned c3 = r3[0], c4 = r4[0], c5 = r5[0];
    unsigned long long b0 = 0ull, b1acc = 0ull;
#pragma unroll
    for (int j = 0; j < 7; j++) {      // dword j -> positions w = 2j, 2j+1
      unsigned n0 = r0[j + 1], n1 = r1[j + 1], n2 = r2[j + 1];
      unsigned n3 = r3[j + 1], n4 = r4[j + 1], n5 = r5[j + 1];
      unsigned q0 = mid(c0, n0), q1 = mid(c1, n1), q2 = mid(c2, n2);
      unsigned q3 = mid(c3, n3), q4 = mid(c4, n4), q5 = mid(c5, n5);
      unsigned by0 = nib(cmax(c0, c1, c2, c3)) |        // h=2h2,   w=2j
                     (nib(cmax(q0, q1, q2, q3)) << 4);  // h=2h2,   w=2j+1
      unsigned by1 = nib(cmax(c2, c3, c4, c5)) |        // h=2h2+1, w=2j
                     (nib(cmax(q2, q3, q4, q5)) << 4);  // h=2h2+1, w=2j+1
      b0 |= (unsigned long long)by0 << (8 * j);
      b1acc |= (unsigned long long)by1 << (8 * j);
      c0 = n0; c1 = n1; c2 = n2; c3 = n3; c4 = n4; c5 = n5;
    }
    // bytes: row 2h2 at base..+6, row 2h2+1 at +7..+13 (2-aligned base)
    unsigned char* p = A4 + (long)b * RSTRIDE + c * 98 + h2 * 14;
    *(unsigned short*)(p + 0)  = (unsigned short)b0;
    *(unsigned short*)(p + 2)  = (unsigned short)(b0 >> 16);
    *(unsigned short*)(p + 4)  = (unsigned short)(b0 >> 32);
    *(unsigned short*)(p + 6)  =
        (unsigned short)(((b0 >> 48) & 0xFFull) | ((b1acc & 0xFFull) << 8));
    *(unsigned short*)(p + 8)  = (unsigned short)(b1acc >> 8);
    *(unsigned short*)(p + 10) = (unsigned short)(b1acc >> 24);
    *(unsigned short*)(p + 12) = (unsigned short)(b1acc >> 40);
  }
}

// ---------- MX-fp4 MFMA GEMM 4096x2048 (K=6400 nib) + BN2 + clip + W3 -------
#define TM 128
#define TN 128
#define BKB 128   // bytes per chunk per row = K 256 nibbles
#define NKC 25    // 3200 / 128

// LDS map:
//  [0,32768)     : buffer 0 (sA 16K | sB 16K)   (tiles: 128 rows x 128 B)
//  [32768,65536) : buffer 1
//  [0,34816)     : epilogue overlay zb[128][136] bf16 (after main loop)
//  [65536,70816) : w3s[10][132] f32
__global__ __launch_bounds__(256, 2) void mm_fp4(
    const unsigned char* __restrict__ A4, const unsigned char* __restrict__ B4,
    const float* __restrict__ b2, const float* __restrict__ g2,
    const float* __restrict__ be2, const float* __restrict__ m2,
    const float* __restrict__ v2, const float* __restrict__ W3,
    float* __restrict__ logits) {
  __shared__ __align__(16) char smem[70816];
  float* w3s = (float*)(smem + 65536);

  const int t = threadIdx.x;
  const int lane = t & 63, wv = t >> 6;
  const int l31 = lane & 31, lh = lane >> 5;
  const int wr = wv >> 1, wc = wv & 1;   // 2x2 wave grid, 64x64 wave tile

  // XCD-aware block swizzle: 512 blocks, 8 XCDs -> each XCD gets 64
  // consecutive swz = 4 M-panels x 16 N-panels.
  const int bid = blockIdx.x;
  const int swz = (bid & 7) * 64 + (bid >> 3);
  const long tileM = (long)(swz >> 4) * TM;
  const long tileN = (long)(swz & 15) * TN;

  // w3s staging: one coalesced 5 KB load per block. The epilogue's read
  // pattern (cls varies per lane -> 8 KB lane stride in W3) would be 64
  // L2 transactions per instruction if read from global (R18: +25 us).
  for (int i = t; i < 1320; i += 256) {
    int cls = i / 132, c = i - cls * 132;
    w3s[i] = (c < 128) ? W3[cls * 2048 + tileN + c] : 0.f;
  }

  // Stage chunk kc into buffer buf: 8 gld_lds per wave (4 A + 4 B).
  // LDS linear (r, sl): off = r*128 + sl*16, holding global slot sl^(r&7)
  // (inverse-swizzled source; frag read applies the same XOR). Proven R6 path.
  auto stage = [&](int buf, int kc) {
    const int kb = kc * BKB;
    char* base = smem + buf * 32768;
#pragma unroll
    for (int i = 0; i < 4; i++) {
      int seg = wv * 4 + i;            // 16 segments x 1 KB = 16 KB
      int o = seg * 1024 + lane * 16;
      int r = o >> 7, sl = (o >> 4) & 7;
      int goff = kb + ((sl ^ (r & 7)) << 4);
      GLD_LDS(A4 + (tileM + r) * RSTRIDE + goff, base + seg * 1024);
      GLD_LDS(B4 + (tileN + r) * RSTRIDE + goff, base + 16384 + seg * 1024);
    }
  };

  f32x16 acc[2][2];
#pragma unroll
  for (int a = 0; a < 2; a++)
#pragma unroll
    for (int q = 0; q < 2; q++) acc[a][q] = (f32x16)0.f;

  stage(0, 0);
  __syncthreads();   // compiler drains vmcnt before s_barrier

  int cur = 0;
  for (int kc = 0; kc < NKC; kc++) {
    if (kc + 1 < NKC) stage(cur ^ 1, kc + 1);  // prefetch overlaps compute
    const char* sAb = smem + cur * 32768;
    const char* sBb = sAb + 16384;
#pragma unroll
    for (int ks = 0; ks < 4; ks++) {   // 4 K-steps of 64 nibbles
      int slot = ks * 2 + lh;          // lane-half lh takes nibbles 0-31/32-63
      i32x8 af[2], bf[2];
#pragma unroll
      for (int mt = 0; mt < 2; mt++) {
        int r = wr * 64 + mt * 32 + l31;
        i32x4 v = *(const i32x4*)(sAb + r * 128 + ((slot ^ (r & 7)) << 4));
        af[mt] = (i32x8){v[0], v[1], v[2], v[3], 0, 0, 0, 0};
      }
#pragma unroll
      for (int nt = 0; nt < 2; nt++) {
        int r = wc * 64 + nt * 32 + l31;
        i32x4 v = *(const i32x4*)(sBb + r * 128 + ((slot ^ (r & 7)) << 4));
        bf[nt] = (i32x8){v[0], v[1], v[2], v[3], 0, 0, 0, 0};
      }
      __builtin_amdgcn_s_setprio(1);
#pragma unroll
      for (int mt = 0; mt < 2; mt++)
#pragma unroll
        for (int nt = 0; nt < 2; nt++)
          acc[mt][nt] = __builtin_amdgcn_mfma_scale_f32_32x32x64_f8f6f4(
              af[mt], bf[nt], acc[mt][nt],
              4, 4,            // cbsz / blgp: fmt 4 = fp4 (e2m1)
              0, 127,          // opsel_a, scale_a = E8M0 127 -> x1.0
              0, 127);         // opsel_b, scale_b
      __builtin_amdgcn_s_setprio(0);
    }
    __syncthreads();   // drains this wave's DMA (vmcnt) + guards buffer swap
    cur ^= 1;
  }

  // ---- epilogue: z = clip(BN2(dot)) as bf16 into LDS, then W3 partials -----
  unsigned short* zb = (unsigned short*)smem;  // [128][136] bf16 = 34816 B
#pragma unroll
  for (int mt = 0; mt < 2; mt++)
#pragma unroll
    for (int nt = 0; nt < 2; nt++) {
      int cl = wc * 64 + nt * 32 + l31;
      int col = (int)tileN + cl;
      float sc = g2[col] * rsqrtf(v2[col] + EPS);
      float off = sc * (b2[col] - m2[col]) + be2[col];
      int rbase = wr * 64 + mt * 32 + 4 * lh;
#pragma unroll
      for (int q = 0; q < 16; q++) {
        int rl = rbase + (q & 3) + 8 * (q >> 2);
        float zz = sc * acc[mt][nt][q] + off;
        zz = fminf(1.f, fmaxf(-1.f, zz));
        __hip_bfloat16 hb = __float2bfloat16(zz);
        zb[rl * 136 + cl] = *(unsigned short*)&hb;
      }
    }
  __syncthreads();

#pragma unroll
  for (int i = 0; i < 5; i++) {
    int task = t + i * 256;           // 1280 tasks = 128 rows x 10 classes
    int row = task / 10, cls = task - row * 10;
    float s = 0.f;
#pragma unroll
    for (int c8 = 0; c8 < 16; c8++) {
      uint4 zB = *(const uint4*)(zb + row * 136 + c8 * 8);  // 8 bf16
      const float* wp = w3s + cls * 132 + c8 * 8;
      float4 w0 = *(const float4*)wp;
      float4 w1 = *(const float4*)(wp + 4);
      s += __uint_as_float(zB.x << 16) * w0.x +
           __uint_as_float(zB.x & 0xffff0000u) * w0.y +
           __uint_as_float(zB.y << 16) * w0.z +
           __uint_as_float(zB.y & 0xffff0000u) * w0.w;
      s += __uint_as_float(zB.z << 16) * w1.x +
           __uint_as_float(zB.z & 0xffff0000u) * w1.y +
           __uint_as_float(zB.w << 16) * w1.z +
           __uint_as_float(zB.w & 0xffff0000u) * w1.w;
    }
    atomicAdd(&logits[(tileM + row) * 10 + cls], s);
  }
}

// ---------- +b3, log_softmax over logits[4096][10] -------------------------
__global__ __launch_bounds__(256) void lsm2(const float* __restrict__ logits,
                                            const float* __restrict__ b3,
                                            float* __restrict__ out) {
  int r = blockIdx.x * 256 + threadIdx.x;
  const float* lr = logits + r * 10;
  float v[10];
#pragma unroll
  for (int j = 0; j < 10; j++) v[j] = lr[j] + b3[j];
  float m = v[0];
#pragma unroll
  for (int j = 1; j < 10; j++) m = fmaxf(m, v[j]);
  float s = 0.f;
#pragma unroll
  for (int j = 0; j < 10; j++) s += expf(v[j] - m);
  float ls = logf(s);
#pragma unroll
  for (int j = 0; j < 10; j++) out[r * 10 + j] = v[j] - m - ls;
}

// ---------------------------------------------------------------------------
extern "C" void kernel_launch(void* const* d_in, const int* in_sizes, int n_in,
                              void* d_out, int out_size, void* d_ws, size_t ws_size,
                              hipStream_t stream) {
  const float* x   = (const float*)d_in[0];
  const float* W1  = (const float*)d_in[1];
  const float* b1  = (const float*)d_in[2];
  const float* g1  = (const float*)d_in[3];
  const float* be1 = (const float*)d_in[4];
  const float* m1  = (const float*)d_in[5];
  const float* v1  = (const float*)d_in[6];
  const float* W2  = (const float*)d_in[7];
  const float* b2  = (const float*)d_in[8];
  const float* g2  = (const float*)d_in[9];
  const float* be2 = (const float*)d_in[10];
  const float* m2  = (const float*)d_in[11];
  const float* v2  = (const float*)d_in[12];
  const float* W3  = (const float*)d_in[13];
  const float* b3  = (const float*)d_in[14];

  char* ws = (char*)d_ws;
  unsigned char* A4 = (unsigned char*)ws;               // 4096*3200 = 13,107,200 B
  unsigned char* B4 = (unsigned char*)(ws + 13107200);  // 2048*3200 = 6,553,600 B
  float* logits = (float*)(ws + 19660800);              // 4096*10*4 = 163,840 B

  stage1<<<6144, 256, 0, stream>>>(x, W1, b1, g1, be1, m1, v1, W2, A4, B4, logits);
  mm_fp4<<<512, 256, 0, stream>>>(A4, B4, b2, g2, be2, m2, v2, W3, logits);
  lsm2<<<16, 256, 0, stream>>>(logits, b3, (float*)d_out);
}